// Round 6
// baseline (326.686 us; speedup 1.0000x reference)
//
#include <hip/hip_runtime.h>
#include <hip/hip_bf16.h>
#include <cmath>

typedef __bf16 bf16;
typedef __bf16 bf16x8 __attribute__((ext_vector_type(8)));
typedef __bf16 bf16x4 __attribute__((ext_vector_type(4)));
typedef float  f32x4  __attribute__((ext_vector_type(4)));

#define B_   2
#define T_   2048
#define D_   1024
#define H_   16
#define DH_  64
#define BT_  (B_ * T_)     // 4096
#define DFF_ (4 * D_)      // 4096

#define GLDS(gp, lp) __builtin_amdgcn_global_load_lds( \
    (const __attribute__((address_space(1))) void*)(gp), \
    (__attribute__((address_space(3))) void*)(lp), 16, 0, 0)

// ---------------- fp32 -> bf16 convert, 4 elems/thread ----------------
__global__ void cvt_f32_bf16(const float* __restrict__ src, bf16* __restrict__ dst, int n) {
    int i = (blockIdx.x * blockDim.x + threadIdx.x) * 4;
    if (i >= n) return;
    float4 v = *(const float4*)(src + i);
    bf16x4 o;
    o[0] = (bf16)v.x; o[1] = (bf16)v.y; o[2] = (bf16)v.z; o[3] = (bf16)v.w;
    *(bf16x4*)(dst + i) = o;
}

__device__ __forceinline__ float gelu_f(float v) {
    return 0.5f * v * (1.0f + erff(v * 0.70710678118654752f));
}

// ---------------- V transpose: vrow [B][T][1024] -> vt [B][1024][T] ----------------
__global__ __launch_bounds__(256) void transpose_v(
    const bf16* __restrict__ vrow, bf16* __restrict__ vt)
{
    __shared__ bf16 tile[64][72];   // stride 72 elems = 144B (16B-aligned rows)
    const int tb = blockIdx.x;      // T tile  (T_/64 = 32)
    const int eb = blockIdx.y;      // e tile  (1024/64 = 16)
    const int b  = blockIdx.z;
    const int c  = threadIdx.x;

    const bf16* src = vrow + ((long)b * T_ + tb * 64) * 1024 + eb * 64;
    #pragma unroll
    for (int j = 0; j < 2; j++) {
        int ch = c + j * 256;
        int r = ch >> 3, s = ch & 7;          // r = t-row, s = 16B chunk
        *(bf16x8*)&tile[r][s * 8] = *(const bf16x8*)&src[(long)r * 1024 + s * 8];
    }
    __syncthreads();
    bf16* dst = vt + ((long)b * 1024 + eb * 64) * 2048 + tb * 64;
    #pragma unroll
    for (int j = 0; j < 2; j++) {
        int ch = c + j * 256;
        int r = ch >> 3, s = ch & 7;          // r = e-row, s = 16B chunk along t
        bf16x8 o;
        #pragma unroll
        for (int k = 0; k < 8; k++) o[k] = tile[s * 8 + k][r];
        *(bf16x8*)&dst[(long)r * 2048 + s * 8] = o;
    }
}

// ---------------- GEMM: C[M,N] = A[M,K] * Bt[N,K]^T  (m97-style 128x128, PROVEN) --
// EPI 1: bf16 out = gelu(acc + bias); EPI 2: f32 out = acc + bias + resid
// EPI 3: QKV split: col < 2048 -> qk rowmajor [M][2048]; col >= 2048 -> vrow [M][1024]
template <int EPI>
__global__ __launch_bounds__(256) void gemm_bt(
    const bf16* __restrict__ A, const bf16* __restrict__ Bt,
    void* __restrict__ outp, void* __restrict__ outp2, const float* __restrict__ bias,
    const float* __restrict__ resid, int M, int N, int K)
{
    __shared__ __align__(16) bf16 As[128 * 32];
    __shared__ __align__(16) bf16 Bs[128 * 32];
    const int tid  = threadIdx.x;
    const int lane = tid & 63;
    const int w    = tid >> 6;
    const int wr   = w >> 1, wc = w & 1;
    const int g    = lane >> 4, cc = lane & 15;
    const int m0   = blockIdx.y * 128, n0 = blockIdx.x * 128;

    f32x4 acc[4][4] = {};

    const int c0 = tid, c1 = tid + 256;
    const bf16* gA0 = A  + (long)(m0 + (c0 >> 2)) * K + ((c0 & 3) << 3);
    const bf16* gA1 = A  + (long)(m0 + (c1 >> 2)) * K + ((c1 & 3) << 3);
    const bf16* gB0 = Bt + (long)(n0 + (c0 >> 2)) * K + ((c0 & 3) << 3);
    const bf16* gB1 = Bt + (long)(n0 + (c1 >> 2)) * K + ((c1 & 3) << 3);
    bf16* lA0 = As + c0 * 8;
    bf16* lA1 = As + c1 * 8;
    bf16* lB0 = Bs + c0 * 8;
    bf16* lB1 = Bs + c1 * 8;

    for (int k0 = 0; k0 < K; k0 += 32) {
        GLDS(gA0 + k0, lA0);
        GLDS(gA1 + k0, lA1);
        GLDS(gB0 + k0, lB0);
        GLDS(gB1 + k0, lB1);
        __syncthreads();

        bf16x8 af[4], bfr[4];
        #pragma unroll
        for (int mi = 0; mi < 4; mi++)
            af[mi] = *(const bf16x8*)&As[(wr * 64 + mi * 16 + cc) * 32 + g * 8];
        #pragma unroll
        for (int ni = 0; ni < 4; ni++)
            bfr[ni] = *(const bf16x8*)&Bs[(wc * 64 + ni * 16 + cc) * 32 + g * 8];
        #pragma unroll
        for (int mi = 0; mi < 4; mi++)
            #pragma unroll
            for (int ni = 0; ni < 4; ni++)
                acc[mi][ni] = __builtin_amdgcn_mfma_f32_16x16x32_bf16(af[mi], bfr[ni], acc[mi][ni], 0, 0, 0);
        __syncthreads();
    }

    #pragma unroll
    for (int mi = 0; mi < 4; mi++) {
        #pragma unroll
        for (int ni = 0; ni < 4; ni++) {
            #pragma unroll
            for (int r = 0; r < 4; r++) {
                int grow = m0 + wr * 64 + mi * 16 + g * 4 + r;
                int gcol = n0 + wc * 64 + ni * 16 + cc;
                float v = acc[mi][ni][r];
                if constexpr (EPI == 3) {
                    if (gcol < 2048)
                        ((bf16*)outp)[(long)grow * 2048 + gcol] = (bf16)v;
                    else
                        ((bf16*)outp2)[(long)grow * 1024 + (gcol - 2048)] = (bf16)v;
                } else if constexpr (EPI == 1) {
                    v += bias[gcol];
                    ((bf16*)outp)[(long)grow * N + gcol] = (bf16)gelu_f(v);
                } else {
                    v += bias[gcol] + resid[(long)grow * N + gcol];
                    ((float*)outp)[(long)grow * N + gcol] = v;
                }
            }
        }
    }
}

// ---------------- flash attention v4: KVBLK=128, single-buffer 48KB, 3 blocks/CU --
// qk: [BT][2048] bf16 (Q cols 0:1024, K cols 1024:2048, per-head 64-wide)
// vt: [B][1024][T] bf16 (V transposed)
// hout[bt,d] = x[bt,d] + attn_out
__global__ __launch_bounds__(256) void attn_kernel(
    const bf16* __restrict__ qk, const bf16* __restrict__ vt,
    const float* __restrict__ x, bf16* __restrict__ hout)
{
    __shared__ __align__(16) bf16 Ks[128 * 64];   // [kv][e] 16KB
    __shared__ __align__(16) bf16 Vs[64 * 128];   // [e][kv] 16KB
    __shared__ __align__(16) bf16 Ps[4][16 * 128]; // per-wave P 4KB each
    const int tid  = threadIdx.x;
    const int lane = tid & 63, w = tid >> 6;
    const int g = lane >> 4, cc = lane & 15;
    const int x7 = cc & 7;
    const int qt = gridDim.x - 1 - blockIdx.x;   // heavy blocks first
    const int hh = blockIdx.y, b = blockIdx.z;
    const int qbase = qt * 64;

    const bf16* qkb   = qk + (long)b * T_ * 2048;
    const bf16* kbase = qkb + 1024 + hh * 64;
    const bf16* vbase = vt + ((long)b * 1024 + hh * 64) * 2048;

    // Q fragment (16 q rows per wave), scale 1/8 folded in (exact pow2 in bf16)
    const long rowQ = (long)(qbase + w * 16 + cc) * 2048 + hh * 64;
    bf16x8 qf0 = *(const bf16x8*)&qkb[rowQ + g * 8];
    bf16x8 qf1 = *(const bf16x8*)&qkb[rowQ + 32 + g * 8];
    #pragma unroll
    for (int j = 0; j < 8; j++) {
        qf0[j] = (bf16)((float)qf0[j] * 0.125f);
        qf1[j] = (bf16)((float)qf1[j] * 0.125f);
    }

    float m_run[4] = {-INFINITY, -INFINITY, -INFINITY, -INFINITY};
    float l_run[4] = {0.f, 0.f, 0.f, 0.f};
    f32x4 o_acc[4] = {};

    const int ntiles = (qbase + 191) >> 7;   // ceil((qbase+64)/128)

    for (int i = 0; i < ntiles; ++i) {
        const int kv0 = i << 7;
        // ---- stage K (128x64) + V (64x128), XOR seg-swizzled both-sides ----
        #pragma unroll
        for (int j = 0; j < 4; j++) {
            int ck = tid + j * 256;
            int kr = ck >> 3;
            int kcol = ((ck & 7) ^ (kr & 7)) << 3;
            GLDS(kbase + (long)(kv0 + kr) * 2048 + kcol, &Ks[ck * 8]);
        }
        #pragma unroll
        for (int j = 0; j < 4; j++) {
            int cv = tid + j * 256;
            int vr = cv >> 4, vs = cv & 15;
            int vseg = (vs & 8) | ((vs & 7) ^ (vr & 7));
            GLDS(vbase + (long)vr * 2048 + kv0 + (vseg << 3), &Vs[cv * 8]);
        }
        __syncthreads();

        // ---- S[16q x 128kv] = (Q/8) K^T : 16 MFMA ----
        f32x4 sacc[8] = {};
        #pragma unroll
        for (int kt = 0; kt < 8; kt++) {
            const bf16* kp = &Ks[(kt * 16 + cc) * 64];
            bf16x8 kf0 = *(const bf16x8*)&kp[(g ^ x7) << 3];
            bf16x8 kf1 = *(const bf16x8*)&kp[((4 | g) ^ x7) << 3];
            sacc[kt] = __builtin_amdgcn_mfma_f32_16x16x32_bf16(qf0, kf0, sacc[kt], 0, 0, 0);
            sacc[kt] = __builtin_amdgcn_mfma_f32_16x16x32_bf16(qf1, kf1, sacc[kt], 0, 0, 0);
        }

        // ---- causal mask (last tile only) ----
        if (i == ntiles - 1) {
            #pragma unroll
            for (int kt = 0; kt < 8; kt++) {
                int kvg = kv0 + kt * 16 + cc;
                #pragma unroll
                for (int r = 0; r < 4; r++) {
                    int qg = qbase + w * 16 + 4 * g + r;
                    if (kvg > qg) sacc[kt][r] = -INFINITY;
                }
            }
        }

        // ---- row max ----
        float pmax[4];
        #pragma unroll
        for (int r = 0; r < 4; r++) {
            float mv = sacc[0][r];
            #pragma unroll
            for (int kt = 1; kt < 8; kt++) mv = fmaxf(mv, sacc[kt][r]);
            pmax[r] = mv;
        }
        #pragma unroll
        for (int mk = 1; mk < 16; mk <<= 1)
            #pragma unroll
            for (int r = 0; r < 4; r++)
                pmax[r] = fmaxf(pmax[r], __shfl_xor(pmax[r], mk));

        // ---- defer-max (T13): rescale only when max grew > 8 ----
        int ok = 1;
        #pragma unroll
        for (int r = 0; r < 4; r++) ok &= (pmax[r] <= m_run[r] + 8.f) ? 1 : 0;
        if (!__all(ok)) {
            float alpha[4];
            #pragma unroll
            for (int r = 0; r < 4; r++) {
                float mn = fmaxf(m_run[r], pmax[r]);
                alpha[r] = __expf(m_run[r] - mn);
                m_run[r] = mn;
                l_run[r] *= alpha[r];
            }
            #pragma unroll
            for (int ec = 0; ec < 4; ec++)
                #pragma unroll
                for (int r = 0; r < 4; r++) o_acc[ec][r] *= alpha[r];
        }

        // ---- P = exp(S - m), row-sum ----
        float rs[4];
        #pragma unroll
        for (int r = 0; r < 4; r++) {
            float s = 0.f;
            #pragma unroll
            for (int kt = 0; kt < 8; kt++) {
                float p = __expf(sacc[kt][r] - m_run[r]);
                sacc[kt][r] = p;
                s += p;
            }
            rs[r] = s;
        }
        #pragma unroll
        for (int mk = 1; mk < 16; mk <<= 1)
            #pragma unroll
            for (int r = 0; r < 4; r++)
                rs[r] += __shfl_xor(rs[r], mk);
        #pragma unroll
        for (int r = 0; r < 4; r++) l_run[r] += rs[r];

        // ---- P: C-layout -> per-wave swizzled LDS ----
        #pragma unroll
        for (int r = 0; r < 4; r++) {
            int qr = 4 * g + r;
            int key = qr & 7;
            #pragma unroll
            for (int kt = 0; kt < 8; kt++) {
                int seg  = (kt << 1) | (cc >> 3);
                int slot = (seg & 8) | ((seg & 7) ^ key);
                Ps[w][qr * 128 + (slot << 3) + (cc & 7)] = (bf16)sacc[kt][r];
            }
        }

        // ---- O += P V : 16 MFMA ----
        #pragma unroll
        for (int ks = 0; ks < 4; ks++) {
            int s_  = ks * 4 + g;
            int slot = (s_ & 8) | ((s_ & 7) ^ x7);
            bf16x8 pf = *(const bf16x8*)&Ps[w][cc * 128 + (slot << 3)];
            #pragma unroll
            for (int ec = 0; ec < 4; ec++) {
                bf16x8 vf = *(const bf16x8*)&Vs[(ec * 16 + cc) * 128 + (slot << 3)];
                o_acc[ec] = __builtin_amdgcn_mfma_f32_16x16x32_bf16(pf, vf, o_acc[ec], 0, 0, 0);
            }
        }
        __syncthreads();   // protect Ks/Vs before next stage
    }

    #pragma unroll
    for (int ec = 0; ec < 4; ec++) {
        #pragma unroll
        for (int r = 0; r < 4; r++) {
            long idx = (long)(b * T_ + qbase + w * 16 + 4 * g + r) * D_ + hh * 64 + ec * 16 + cc;
            hout[idx] = (bf16)(x[idx] + o_acc[ec][r] / l_run[r]);
        }
    }
}

// ---------------- launch ----------------
extern "C" void kernel_launch(void* const* d_in, const int* in_sizes, int n_in,
                              void* d_out, int out_size, void* d_ws, size_t ws_size,
                              hipStream_t stream) {
    const float* x  = (const float*)d_in[0];
    const float* wq = (const float*)d_in[2];
    const float* wk = (const float*)d_in[3];
    const float* wv = (const float*)d_in[4];
    const float* w1 = (const float*)d_in[5];
    const float* b1 = (const float*)d_in[6];
    const float* w2 = (const float*)d_in[7];
    const float* b2 = (const float*)d_in[8];
    float* out = (float*)d_out;

    char* ws = (char*)d_ws;
    bf16* xb   = (bf16*)(ws);                  // [4096,1024]   8 MB
    bf16* wall = (bf16*)(ws + (8L  << 20));    // [3072,1024]   6 MB
    bf16* w1b  = (bf16*)(ws + (14L << 20));    // [4096,1024]   8 MB
    bf16* w2b  = (bf16*)(ws + (22L << 20));    // [1024,4096]   8 MB
    bf16* qkb  = (bf16*)(ws + (30L << 20));    // [4096,2048]  16 MB
    bf16* vtb  = (bf16*)(ws + (46L << 20));    // [2,1024,2048] 8 MB
    bf16* hbuf = (bf16*)(ws + (54L << 20));    // [4096,1024]   8 MB (also vrow scratch)
    bf16* abuf = (bf16*)(ws + (62L << 20));    // [4096,4096]  32 MB
    bf16* vrow = hbuf;  // [4096,1024] 8 MB; consumed by transpose_v BEFORE attn writes hbuf

    auto cvt = [&](const float* s, bf16* d, int n) {
        cvt_f32_bf16<<<(n / 4 + 255) / 256, 256, 0, stream>>>(s, d, n);
    };
    cvt(x,  xb,              BT_ * D_);
    cvt(wq, wall,            D_ * D_);
    cvt(wk, wall + D_ * D_,  D_ * D_);
    cvt(wv, wall + 2 * D_ * D_, D_ * D_);
    cvt(w1, w1b, DFF_ * D_);
    cvt(w2, w2b, D_ * DFF_);

    // QKV projection: -> qk [4096,2048] + vrow [4096,1024] (all coalesced)
    gemm_bt<3><<<dim3(3 * D_ / 128, BT_ / 128), 256, 0, stream>>>(
        xb, wall, qkb, vrow, nullptr, nullptr, BT_, 3 * D_, D_);

    // V transpose: vrow -> vt [2][1024][2048]
    transpose_v<<<dim3(T_ / 64, D_ / 64, B_), 256, 0, stream>>>(vrow, vtb);

    // attention + residual: hbuf = x + attn_out  (overwrites vrow, already consumed)
    attn_kernel<<<dim3(T_ / 64, H_, B_), 256, 0, stream>>>(qkb, vtb, x, hbuf);

    // FFN1: gelu(h @ w1^T + b1) -> [4096,4096] bf16
    gemm_bt<1><<<dim3(DFF_ / 128, BT_ / 128), 256, 0, stream>>>(
        hbuf, w1b, abuf, nullptr, b1, nullptr, BT_, DFF_, D_);

    // FFN2 + bias + residual x -> out fp32 [4096,1024]
    gemm_bt<2><<<dim3(D_ / 128, BT_ / 128), 256, 0, stream>>>(
        abuf, w2b, out, nullptr, b2, x, BT_, D_, DFF_);
}

// Round 7
// 299.689 us; speedup vs baseline: 1.0901x; 1.0901x over previous
//
#include <hip/hip_runtime.h>
#include <hip/hip_bf16.h>
#include <cmath>

typedef __bf16 bf16;
typedef __bf16 bf16x8 __attribute__((ext_vector_type(8)));
typedef __bf16 bf16x4 __attribute__((ext_vector_type(4)));
typedef __bf16 bf16x2 __attribute__((ext_vector_type(2)));
typedef float  f32x4  __attribute__((ext_vector_type(4)));
typedef float  f32x16 __attribute__((ext_vector_type(16)));
typedef int    i32x4  __attribute__((ext_vector_type(4)));

#define B_   2
#define T_   2048
#define D_   1024
#define H_   16
#define DH_  64
#define BT_  (B_ * T_)     // 4096
#define DFF_ (4 * D_)      // 4096

#define GLDS(gp, lp) __builtin_amdgcn_global_load_lds( \
    (const __attribute__((address_space(1))) void*)(gp), \
    (__attribute__((address_space(3))) void*)(lp), 16, 0, 0)

// ---------------- fp32 -> bf16 convert, 4 elems/thread ----------------
__global__ void cvt_f32_bf16(const float* __restrict__ src, bf16* __restrict__ dst, int n) {
    int i = (blockIdx.x * blockDim.x + threadIdx.x) * 4;
    if (i >= n) return;
    float4 v = *(const float4*)(src + i);
    bf16x4 o;
    o[0] = (bf16)v.x; o[1] = (bf16)v.y; o[2] = (bf16)v.z; o[3] = (bf16)v.w;
    *(bf16x4*)(dst + i) = o;
}

__device__ __forceinline__ float gelu_f(float v) {
    return 0.5f * v * (1.0f + erff(v * 0.70710678118654752f));
}

__device__ __forceinline__ int pkbf(float a, float b) {
    bf16x2 v; v[0] = (bf16)a; v[1] = (bf16)b;
    return __builtin_bit_cast(int, v);
}

// ---------------- V transpose: vrow [B][T][1024] -> vt [B][1024][T] ----------------
__global__ __launch_bounds__(256) void transpose_v(
    const bf16* __restrict__ vrow, bf16* __restrict__ vt)
{
    __shared__ bf16 tile[64][72];
    const int tb = blockIdx.x;
    const int eb = blockIdx.y;
    const int b  = blockIdx.z;
    const int c  = threadIdx.x;

    const bf16* src = vrow + ((long)b * T_ + tb * 64) * 1024 + eb * 64;
    #pragma unroll
    for (int j = 0; j < 2; j++) {
        int ch = c + j * 256;
        int r = ch >> 3, s = ch & 7;
        *(bf16x8*)&tile[r][s * 8] = *(const bf16x8*)&src[(long)r * 1024 + s * 8];
    }
    __syncthreads();
    bf16* dst = vt + ((long)b * 1024 + eb * 64) * 2048 + tb * 64;
    #pragma unroll
    for (int j = 0; j < 2; j++) {
        int ch = c + j * 256;
        int r = ch >> 3, s = ch & 7;
        bf16x8 o;
        #pragma unroll
        for (int k = 0; k < 8; k++) o[k] = tile[s * 8 + k][r];
        *(bf16x8*)&dst[(long)r * 2048 + s * 8] = o;
    }
}

// ---------------- GEMM: C[M,N] = A[M,K] * Bt[N,K]^T  (m97-style 128x128, PROVEN) --
template <int EPI>
__global__ __launch_bounds__(256) void gemm_bt(
    const bf16* __restrict__ A, const bf16* __restrict__ Bt,
    void* __restrict__ outp, void* __restrict__ outp2, const float* __restrict__ bias,
    const float* __restrict__ resid, int M, int N, int K)
{
    __shared__ __align__(16) bf16 As[128 * 32];
    __shared__ __align__(16) bf16 Bs[128 * 32];
    const int tid  = threadIdx.x;
    const int lane = tid & 63;
    const int w    = tid >> 6;
    const int wr   = w >> 1, wc = w & 1;
    const int g    = lane >> 4, cc = lane & 15;
    const int m0   = blockIdx.y * 128, n0 = blockIdx.x * 128;

    f32x4 acc[4][4] = {};

    const int c0 = tid, c1 = tid + 256;
    const bf16* gA0 = A  + (long)(m0 + (c0 >> 2)) * K + ((c0 & 3) << 3);
    const bf16* gA1 = A  + (long)(m0 + (c1 >> 2)) * K + ((c1 & 3) << 3);
    const bf16* gB0 = Bt + (long)(n0 + (c0 >> 2)) * K + ((c0 & 3) << 3);
    const bf16* gB1 = Bt + (long)(n0 + (c1 >> 2)) * K + ((c1 & 3) << 3);
    bf16* lA0 = As + c0 * 8;
    bf16* lA1 = As + c1 * 8;
    bf16* lB0 = Bs + c0 * 8;
    bf16* lB1 = Bs + c1 * 8;

    for (int k0 = 0; k0 < K; k0 += 32) {
        GLDS(gA0 + k0, lA0);
        GLDS(gA1 + k0, lA1);
        GLDS(gB0 + k0, lB0);
        GLDS(gB1 + k0, lB1);
        __syncthreads();

        bf16x8 af[4], bfr[4];
        #pragma unroll
        for (int mi = 0; mi < 4; mi++)
            af[mi] = *(const bf16x8*)&As[(wr * 64 + mi * 16 + cc) * 32 + g * 8];
        #pragma unroll
        for (int ni = 0; ni < 4; ni++)
            bfr[ni] = *(const bf16x8*)&Bs[(wc * 64 + ni * 16 + cc) * 32 + g * 8];
        #pragma unroll
        for (int mi = 0; mi < 4; mi++)
            #pragma unroll
            for (int ni = 0; ni < 4; ni++)
                acc[mi][ni] = __builtin_amdgcn_mfma_f32_16x16x32_bf16(af[mi], bfr[ni], acc[mi][ni], 0, 0, 0);
        __syncthreads();
    }

    #pragma unroll
    for (int mi = 0; mi < 4; mi++) {
        #pragma unroll
        for (int ni = 0; ni < 4; ni++) {
            #pragma unroll
            for (int r = 0; r < 4; r++) {
                int grow = m0 + wr * 64 + mi * 16 + g * 4 + r;
                int gcol = n0 + wc * 64 + ni * 16 + cc;
                float v = acc[mi][ni][r];
                if constexpr (EPI == 3) {
                    if (gcol < 2048)
                        ((bf16*)outp)[(long)grow * 2048 + gcol] = (bf16)v;
                    else
                        ((bf16*)outp2)[(long)grow * 1024 + (gcol - 2048)] = (bf16)v;
                } else if constexpr (EPI == 1) {
                    v += bias[gcol];
                    ((bf16*)outp)[(long)grow * N + gcol] = (bf16)gelu_f(v);
                } else {
                    v += bias[gcol] + resid[(long)grow * N + gcol];
                    ((float*)outp)[(long)grow * N + gcol] = v;
                }
            }
        }
    }
}

// ---------------- flash attention v5: swapped-QK 32x32 MFMA, in-register softmax ---
// qk: [BT][2048] bf16 (Q cols 0:1024, K cols 1024:2048, per-head 64-wide)
// vt: [B][1024][T] bf16 (V transposed)
// Per wave: 32 q rows; block = 4 waves = 128 q rows. KVBLK=64, dbuf LDS.
// S^T = mfma(A=K, B=Q): lane (q=lane&31, hi=lane>>5) holds kv rows (r&3)+8(r>>2)+4hi.
__global__ __launch_bounds__(256) void attn_kernel(
    const bf16* __restrict__ qk, const bf16* __restrict__ vt,
    const float* __restrict__ x, bf16* __restrict__ hout)
{
    __shared__ __align__(16) bf16 Ks[2][64 * 64];   // [kv][e] seg-swizzled, 8KB each
    __shared__ __align__(16) bf16 Vs[2][64 * 64];   // [e][kv] seg-swizzled, 8KB each
    const int tid  = threadIdx.x;
    const int lane = tid & 63, w = tid >> 6;
    const int l31 = lane & 31, hi = lane >> 5;
    const int qb = gridDim.x - 1 - blockIdx.x;   // heavy blocks first
    const int hh = blockIdx.y, b = blockIdx.z;
    const int qbase = qb * 128;
    const int qw0 = qbase + w * 32;              // wave's first q row
    const int qg  = qw0 + l31;                   // lane's q row

    const bf16* qkb   = qk + (long)b * T_ * 2048;
    const bf16* kbase = qkb + 1024 + hh * 64;
    const bf16* vbase = vt + ((long)b * 1024 + hh * 64) * 2048;

    // Q B-frags: col=q=l31, k = 8*hi + j within each 16-wide e-slice; scale folded in
    bf16x8 qf[4];
    {
        const bf16* qrow = qkb + (long)qg * 2048 + hh * 64;
        #pragma unroll
        for (int ks = 0; ks < 4; ks++) {
            bf16x8 v = *(const bf16x8*)&qrow[ks * 16 + hi * 8];
            #pragma unroll
            for (int j = 0; j < 8; j++) v[j] = (bf16)((float)v[j] * 0.125f);
            qf[ks] = v;
        }
    }

    float m_run = -INFINITY, l_run = 0.f;
    f32x16 o0 = {}, o1 = {};

    const int ntiles = (qbase >> 6) + 2;              // block tiles (64-kv each)
    const int my_end = ((qw0 + 31) >> 6) + 1;         // this wave's causal end

    auto stage = [&](int i) {
        const int buf = i & 1;
        const long kv0 = (long)i << 6;
        #pragma unroll
        for (int j = 0; j < 2; j++) {
            int c = tid + j * 256;
            int r = c >> 3, s = c & 7;
            int seg = (s ^ (r & 7)) << 3;
            GLDS(kbase + (kv0 + r) * 2048 + seg, &Ks[buf][c * 8]);
            GLDS(vbase + (long)r * 2048 + kv0 + seg, &Vs[buf][c * 8]);
        }
    };

    stage(0);
    __syncthreads();

    for (int i = 0; i < ntiles; ++i) {
        const int buf = i & 1;
        const int kv0 = i << 6;
        if (i + 1 < ntiles) stage(i + 1);   // other buffer; prior readers done (barrier)

        if (i < my_end) {
            // ---- S^T: two 32-kv subtiles, 4 MFMA each ----
            f32x16 s0 = {}, s1 = {};
            const int xk = l31 & 7;
            #pragma unroll
            for (int ks = 0; ks < 4; ks++) {
                int slot = ((2 * ks + hi) ^ xk) << 3;
                bf16x8 kf0 = *(const bf16x8*)&Ks[buf][l31 * 64 + slot];
                bf16x8 kf1 = *(const bf16x8*)&Ks[buf][(32 + l31) * 64 + slot];
                s0 = __builtin_amdgcn_mfma_f32_32x32x16_bf16(kf0, qf[ks], s0, 0, 0, 0);
                s1 = __builtin_amdgcn_mfma_f32_32x32x16_bf16(kf1, qf[ks], s1, 0, 0, 0);
            }

            // ---- causal mask (diagonal region only) ----
            if (kv0 + 64 > qw0) {
                #pragma unroll
                for (int r = 0; r < 16; r++) {
                    int kvr = kv0 + (r & 3) + 8 * (r >> 2) + 4 * hi;
                    if (kvr > qg)      s0[r] = -INFINITY;
                    if (kvr + 32 > qg) s1[r] = -INFINITY;
                }
            }

            // ---- row max: 31 in-lane + 1 swap ----
            float pm = s0[0];
            #pragma unroll
            for (int r = 1; r < 16; r++) pm = fmaxf(pm, s0[r]);
            #pragma unroll
            for (int r = 0; r < 16; r++) pm = fmaxf(pm, s1[r]);
            pm = fmaxf(pm, __shfl_xor(pm, 32));

            // ---- defer-max (T13) ----
            if (!__all(pm <= m_run + 8.f)) {
                float mn = fmaxf(m_run, pm);
                float al = __expf(m_run - mn);
                m_run = mn;
                l_run *= al;
                #pragma unroll
                for (int r = 0; r < 16; r++) {
                    float av = __shfl(al, (r & 3) + 8 * (r >> 2) + 4 * hi);
                    o0[r] *= av; o1[r] *= av;
                }
            }

            // ---- P = exp(S - m), in-lane sum + 1 swap ----
            float rs = 0.f;
            #pragma unroll
            for (int r = 0; r < 16; r++) { float p = __expf(s0[r] - m_run); s0[r] = p; rs += p; }
            #pragma unroll
            for (int r = 0; r < 16; r++) { float p = __expf(s1[r] - m_run); s1[r] = p; rs += p; }
            rs += __shfl_xor(rs, 32);
            l_run += rs;

            // ---- pack P -> A-frags (4 slices of 16 kv), dword exchange across hi ----
            i32x4 pw[4];
            {
                int d0[4], d1[4];
                #pragma unroll
                for (int m = 0; m < 4; m++) {
                    d0[m] = pkbf(s0[4 * m],     s0[4 * m + 1]);
                    d1[m] = pkbf(s0[4 * m + 2], s0[4 * m + 3]);
                }
                #pragma unroll
                for (int k2 = 0; k2 < 2; k2++) {
                    int r0 = __shfl_xor(d0[2 * k2 + 1 - hi], 32);
                    int r1 = __shfl_xor(d1[2 * k2 + 1 - hi], 32);
                    i32x4 t;
                    t[0] = hi ? r0 : d0[2 * k2];
                    t[1] = hi ? r1 : d1[2 * k2];
                    t[2] = hi ? d0[2 * k2 + 1] : r0;
                    t[3] = hi ? d1[2 * k2 + 1] : r1;
                    pw[k2] = t;
                }
            }
            {
                int d0[4], d1[4];
                #pragma unroll
                for (int m = 0; m < 4; m++) {
                    d0[m] = pkbf(s1[4 * m],     s1[4 * m + 1]);
                    d1[m] = pkbf(s1[4 * m + 2], s1[4 * m + 3]);
                }
                #pragma unroll
                for (int k2 = 0; k2 < 2; k2++) {
                    int r0 = __shfl_xor(d0[2 * k2 + 1 - hi], 32);
                    int r1 = __shfl_xor(d1[2 * k2 + 1 - hi], 32);
                    i32x4 t;
                    t[0] = hi ? r0 : d0[2 * k2];
                    t[1] = hi ? r1 : d1[2 * k2];
                    t[2] = hi ? d0[2 * k2 + 1] : r0;
                    t[3] = hi ? d1[2 * k2 + 1] : r1;
                    pw[2 + k2] = t;
                }
            }

            // ---- O += P V : 8 MFMA ----
            #pragma unroll
            for (int sl = 0; sl < 4; sl++) {
                bf16x8 pa = __builtin_bit_cast(bf16x8, pw[sl]);
                int slot = ((2 * sl + hi) ^ xk) << 3;
                bf16x8 vf0 = *(const bf16x8*)&Vs[buf][l31 * 64 + slot];
                bf16x8 vf1 = *(const bf16x8*)&Vs[buf][(32 + l31) * 64 + slot];
                o0 = __builtin_amdgcn_mfma_f32_32x32x16_bf16(pa, vf0, o0, 0, 0, 0);
                o1 = __builtin_amdgcn_mfma_f32_32x32x16_bf16(pa, vf1, o1, 0, 0, 0);
            }
        }
        __syncthreads();   // readers of buf done + prefetch (other buf) drained
    }

    // ---- epilogue: O rows = q = crow(reg,hi); cols = e = 32h + l31 ----
    #pragma unroll
    for (int r = 0; r < 16; r++) {
        int qr = (r & 3) + 8 * (r >> 2) + 4 * hi;
        float lr = __shfl(l_run, qr);
        int grow = qbase + w * 32 + qr;
        long base = ((long)b * T_ + grow) * 1024 + hh * 64 + l31;
        hout[base]      = (bf16)(x[base]      + o0[r] / lr);
        hout[base + 32] = (bf16)(x[base + 32] + o1[r] / lr);
    }
}

// ---------------- launch ----------------
extern "C" void kernel_launch(void* const* d_in, const int* in_sizes, int n_in,
                              void* d_out, int out_size, void* d_ws, size_t ws_size,
                              hipStream_t stream) {
    const float* x  = (const float*)d_in[0];
    const float* wq = (const float*)d_in[2];
    const float* wk = (const float*)d_in[3];
    const float* wv = (const float*)d_in[4];
    const float* w1 = (const float*)d_in[5];
    const float* b1 = (const float*)d_in[6];
    const float* w2 = (const float*)d_in[7];
    const float* b2 = (const float*)d_in[8];
    float* out = (float*)d_out;

    char* ws = (char*)d_ws;
    bf16* xb   = (bf16*)(ws);                  // [4096,1024]   8 MB
    bf16* wall = (bf16*)(ws + (8L  << 20));    // [3072,1024]   6 MB
    bf16* w1b  = (bf16*)(ws + (14L << 20));    // [4096,1024]   8 MB
    bf16* w2b  = (bf16*)(ws + (22L << 20));    // [1024,4096]   8 MB
    bf16* qkb  = (bf16*)(ws + (30L << 20));    // [4096,2048]  16 MB
    bf16* vtb  = (bf16*)(ws + (46L << 20));    // [2,1024,2048] 8 MB
    bf16* hbuf = (bf16*)(ws + (54L << 20));    // [4096,1024]   8 MB (also vrow scratch)
    bf16* abuf = (bf16*)(ws + (62L << 20));    // [4096,4096]  32 MB
    bf16* vrow = hbuf;  // consumed by transpose_v BEFORE attn writes hbuf

    auto cvt = [&](const float* s, bf16* d, int n) {
        cvt_f32_bf16<<<(n / 4 + 255) / 256, 256, 0, stream>>>(s, d, n);
    };
    cvt(x,  xb,              BT_ * D_);
    cvt(wq, wall,            D_ * D_);
    cvt(wk, wall + D_ * D_,  D_ * D_);
    cvt(wv, wall + 2 * D_ * D_, D_ * D_);
    cvt(w1, w1b, DFF_ * D_);
    cvt(w2, w2b, D_ * DFF_);

    // QKV projection: -> qk [4096,2048] + vrow [4096,1024]
    gemm_bt<3><<<dim3(3 * D_ / 128, BT_ / 128), 256, 0, stream>>>(
        xb, wall, qkb, vrow, nullptr, nullptr, BT_, 3 * D_, D_);

    // V transpose: vrow -> vt [2][1024][2048]
    transpose_v<<<dim3(T_ / 64, D_ / 64, B_), 256, 0, stream>>>(vrow, vtb);

    // attention + residual: hbuf = x + attn_out
    attn_kernel<<<dim3(T_ / 128, H_, B_), 256, 0, stream>>>(qkb, vtb, x, hbuf);

    // FFN1: gelu(h @ w1^T + b1) -> [4096,4096] bf16
    gemm_bt<1><<<dim3(DFF_ / 128, BT_ / 128), 256, 0, stream>>>(
        hbuf, w1b, abuf, nullptr, b1, nullptr, BT_, DFF_, D_);

    // FFN2 + bias + residual x -> out fp32 [4096,1024]
    gemm_bt<2><<<dim3(D_ / 128, BT_ / 128), 256, 0, stream>>>(
        abuf, w2b, out, nullptr, b2, x, BT_, D_, DFF_);
}